// Round 10
// baseline (34.504 us; speedup 1.0000x reference)
//
#include <hip/hip_runtime.h>

#define IMG_H 1024
#define IMG_W 1024

#define CC  (-0.1803368801111244f)     // -(1/8)*log2(e)
#define WS1 (-2.8853900817779270e-4f)  // log2(exp(-1/5000))
#define WS2 (-5.7707801635558540e-4f)  // log2(exp(-2/5000))

// trans-pipe exp2 (v_exp_f32)
__device__ __forceinline__ float edgew_t(float u, float v, float ws) {
    float d = u - v;
    return __builtin_amdgcn_exp2f(fmaf(d * d, CC, ws));
}

// full-rate-VALU exp2: t=y+1.5*2^23 extracts n=round(y); f=y-n in [-0.5,0.5];
// degree-4 poly; exponent reassembled via (bits(t)<<23) (exact, low bits of
// 0x4B400000 are zero). abs err ~5e-5. Valid for y in (-120, 0].
__device__ __forceinline__ float exp2_poly(float y) {
    float t = y + 12582912.0f;
    float f = y - (t - 12582912.0f);
    float p = fmaf(f, 0.0096181291f, 0.0555041087f);
    p = fmaf(f, p, 0.2402265070f);
    p = fmaf(f, p, 0.6931471806f);
    p = fmaf(f, p, 1.0f);
    return __int_as_float((__float_as_int(t) << 23) + __float_as_int(p));
}

// VALU-pipe edge weight (for diagonals)
__device__ __forceinline__ float edgew_p(float u, float v, float ws) {
    float d = u - v;
    return exp2_poly(fmaf(d * d, CC, ws));
}

__global__ __launch_bounds__(256) void EdgePreserve_kernel(const float* __restrict__ x,
                                                           float* __restrict__ out) {
    const int t   = threadIdx.x;
    const int bid = blockIdx.x;         // b*64 + pool_row
    const int b   = bid >> 6;
    const int pr  = bid & 63;
    const int r0  = pr << 4;
    const int c0  = t << 2;             // 4 cols per thread; block covers full row

    const float* base = x + (size_t)b * (IMG_H * IMG_W);
    const int cl = (c0 == 0) ? 1 : c0 - 1;                 // reflect left halo col
    const int cr = (c0 + 4 >= IMG_W) ? IMG_W - 2 : c0 + 4; // reflect right halo col

    // 5 row buffers, named scalars only. After top-of-iter rotation:
    // a=r-1, b=r, k=r+1, p=r+2, q=free -> prefetch row r+3 into q.
    float a0,a1,a2,a3,a4,a5, b0,b1,b2,b3,b4,b5, k0,k1,k2,k3,k4,k5,
          p0,p1,p2,p3,p4,p5, q0,q1,q2,q3,q4,q5;

#define LOADROW(qr, d0,d1,d2,d3,d4,d5) { \
    int _r = r0 + (qr); \
    int _rr = (_r < 0) ? -_r : ((_r >= IMG_H) ? (2*IMG_H-2-_r) : _r); \
    const float* _rp = base + _rr * IMG_W; \
    float4 _v = *reinterpret_cast<const float4*>(_rp + c0); \
    d0 = _rp[cl]; d1 = _v.x; d2 = _v.y; d3 = _v.z; d4 = _v.w; d5 = _rp[cr]; }

    // prologue: b=row -1, k=row 0, p=row 1, q=row 2 (a filled by iter-0 rotate)
    LOADROW(-1, b0,b1,b2,b3,b4,b5)
    LOADROW( 0, k0,k1,k2,k3,k4,k5)
    LOADROW( 1, p0,p1,p2,p3,p4,p5)
    LOADROW( 2, q0,q1,q2,q3,q4,q5)

    // carried upper-row edges for iter 0 (rows -1 and 0):
    float pV1  = edgew_t(b1,k1,WS1), pV2  = edgew_t(b2,k2,WS1),
          pV3  = edgew_t(b3,k3,WS1), pV4  = edgew_t(b4,k4,WS1);
    float pDL2 = edgew_p(b2,k1,WS2), pDL3 = edgew_p(b3,k2,WS2),
          pDL4 = edgew_p(b4,k3,WS2), pDL5 = edgew_p(b5,k4,WS2);
    float pDR0 = edgew_p(b0,k1,WS2), pDR1 = edgew_p(b1,k2,WS2),
          pDR2 = edgew_p(b2,k3,WS2), pDR3 = edgew_p(b3,k4,WS2);

    float psum = 0.0f;

    // Partial unroll: body ~4x250 insts ~ 8KB, fits I$ (full unroll was ~25-45KB).
    #pragma unroll 4
    for (int r = 0; r < 16; ++r) {
        // rotate, freeing q...
        a0=b0;a1=b1;a2=b2;a3=b3;a4=b4;a5=b5;
        b0=k0;b1=k1;b2=k2;b3=k3;b4=k4;b5=k5;
        k0=p0;k1=p1;k2=p2;k3=p3;k4=p4;k5=p5;
        p0=q0;p1=q1;p2=q2;p3=q3;p4=q4;p5=q5;
        // ...prefetch row r+3 (first consumed as k in iter r+2)
        if (r < 14) { LOADROW(r+3, q0,q1,q2,q3,q4,q5) }

        // trans-pipe edges: horizontal + vertical
        float H0 = edgew_t(b0,b1,WS1), H1 = edgew_t(b1,b2,WS1), H2 = edgew_t(b2,b3,WS1),
              H3 = edgew_t(b3,b4,WS1), H4 = edgew_t(b4,b5,WS1);
        float V1 = edgew_t(b1,k1,WS1), V2 = edgew_t(b2,k2,WS1),
              V3 = edgew_t(b3,k3,WS1), V4 = edgew_t(b4,k4,WS1);
        // VALU-pipe edges: diagonals
        float DL1 = edgew_p(b1,k0,WS2), DL2 = edgew_p(b2,k1,WS2), DL3 = edgew_p(b3,k2,WS2),
              DL4 = edgew_p(b4,k3,WS2), DL5 = edgew_p(b5,k4,WS2);
        float DR0 = edgew_p(b0,k1,WS2), DR1 = edgew_p(b1,k2,WS2), DR2 = edgew_p(b2,k3,WS2),
              DR3 = edgew_p(b3,k4,WS2), DR4 = edgew_p(b4,k5,WS2);

#define PIXEL(am,ac,ap, bm,bc,bp, km,kc,kp, wAL,wAC,wAR, wBL,wBR, wCL,wCV,wCR) { \
        float num = bc; \
        num = fmaf(wAL, am, num); num = fmaf(wAC, ac, num); num = fmaf(wAR, ap, num); \
        num = fmaf(wBL, bm, num); num = fmaf(wBR, bp, num); \
        num = fmaf(wCL, km, num); num = fmaf(wCV, kc, num); num = fmaf(wCR, kp, num); \
        float den = 1.0f + (((wAL + wAC) + (wAR + wBL)) + ((wBR + wCL) + (wCV + wCR))); \
        psum = fmaf(num, __builtin_amdgcn_rcpf(den), psum); }

        PIXEL(a0,a1,a2, b0,b1,b2, k0,k1,k2, pDR0,pV1,pDL2, H0,H1, DL1,V1,DR1)
        PIXEL(a1,a2,a3, b1,b2,b3, k1,k2,k3, pDR1,pV2,pDL3, H1,H2, DL2,V2,DR2)
        PIXEL(a2,a3,a4, b2,b3,b4, k2,k3,k4, pDR2,pV3,pDL4, H2,H3, DL3,V3,DR3)
        PIXEL(a3,a4,a5, b3,b4,b5, k3,k4,k5, pDR3,pV4,pDL5, H3,H4, DL4,V4,DR4)
#undef PIXEL

        // carried upper-row weights = this iter's B-K edges
        pV1=V1;  pV2=V2;  pV3=V3;  pV4=V4;
        pDL2=DL2;pDL3=DL3;pDL4=DL4;pDL5=DL5;
        pDR0=DR0;pDR1=DR1;pDR2=DR2;pDR3=DR3;
    }
#undef LOADROW

    // pool block = 16 cols = 4 lanes (4 cols each); 16 rows accumulated
    psum += __shfl_xor(psum, 1);
    psum += __shfl_xor(psum, 2);

    if ((t & 3) == 0) {
        out[(size_t)bid * 64 + (t >> 2)] = psum * (1.0f / 256.0f);
    }
}

extern "C" void kernel_launch(void* const* d_in, const int* in_sizes, int n_in,
                              void* d_out, int out_size, void* d_ws, size_t ws_size,
                              hipStream_t stream) {
    const float* x = (const float*)d_in[0];
    float* out     = (float*)d_out;
    // grid: 16 batches * 64 pool rows = 1024 blocks of 256 threads (4 cols x 16 rows)
    EdgePreserve_kernel<<<dim3(16 * 64), dim3(256), 0, stream>>>(x, out);
}

// Round 11
// 30.855 us; speedup vs baseline: 1.1183x; 1.1183x over previous
//
#include <hip/hip_runtime.h>

#define IMG_H 1024
#define IMG_W 1024

#define CC  (-0.1803368801111244f)     // -(1/8)*log2(e)
#define WS1 (-2.8853900817779270e-4f)  // log2(exp(-1/5000))
#define WS2 (-5.7707801635558540e-4f)  // log2(exp(-2/5000))

__device__ __forceinline__ float edgew(float u, float v, float ws) {
    float d = u - v;
    return __builtin_amdgcn_exp2f(fmaf(d * d, CC, ws));
}

// R7 inner structure (best measured), halved rows per block for 2x occupancy.
__global__ __launch_bounds__(256, 8) void EdgePreserve_kernel(const float* __restrict__ x,
                                                              float* __restrict__ out) {
    const int t    = threadIdx.x;
    const int bid  = blockIdx.x;        // ((b*64 + pr)<<1) | half
    const int half = bid & 1;
    const int pr   = (bid >> 1) & 63;
    const int b    = bid >> 7;
    const int r0   = (pr << 4) + (half << 3);  // 8-row half-strip
    const int c0   = t << 2;            // 4 cols per thread; block covers full row

    const float* base = x + (size_t)b * (IMG_H * IMG_W);
    const int cl = (c0 == 0) ? 1 : c0 - 1;                 // reflect left halo col
    const int cr = (c0 + 4 >= IMG_W) ? IMG_W - 2 : c0 + 4; // reflect right halo col

    // 4 row buffers, named scalars only: a=r-1, b=r, k=r+1, p=prefetch(r+2/r+3)
    float a0,a1,a2,a3,a4,a5, b0,b1,b2,b3,b4,b5, k0,k1,k2,k3,k4,k5, p0,p1,p2,p3,p4,p5;

#define LOADROW(q, d0,d1,d2,d3,d4,d5) { \
    int _r = r0 + (q); \
    int _rr = (_r < 0) ? -_r : ((_r >= IMG_H) ? (2*IMG_H-2-_r) : _r); \
    const float* _rp = base + _rr * IMG_W; \
    float4 _v = *reinterpret_cast<const float4*>(_rp + c0); \
    d0 = _rp[cl]; d1 = _v.x; d2 = _v.y; d3 = _v.z; d4 = _v.w; d5 = _rp[cr]; }

    LOADROW(-1, a0,a1,a2,a3,a4,a5)
    LOADROW( 0, b0,b1,b2,b3,b4,b5)
    LOADROW( 1, k0,k1,k2,k3,k4,k5)
    LOADROW( 2, p0,p1,p2,p3,p4,p5)

    // carried upper-row edges (between rows r0-1 and r0):
    float pV1 = edgew(a1,b1,WS1), pV2 = edgew(a2,b2,WS1), pV3 = edgew(a3,b3,WS1), pV4 = edgew(a4,b4,WS1);
    float pDL2 = edgew(a2,b1,WS2), pDL3 = edgew(a3,b2,WS2), pDL4 = edgew(a4,b3,WS2), pDL5 = edgew(a5,b4,WS2);
    float pDR0 = edgew(a0,b1,WS2), pDR1 = edgew(a1,b2,WS2), pDR2 = edgew(a2,b3,WS2), pDR3 = edgew(a3,b4,WS2);

    float psum = 0.0f;

    #pragma unroll
    for (int r = 0; r < 8; ++r) {
        // horizontal edges within row B
        float H0 = edgew(b0,b1,WS1), H1 = edgew(b1,b2,WS1), H2 = edgew(b2,b3,WS1),
              H3 = edgew(b3,b4,WS1), H4 = edgew(b4,b5,WS1);
        // B-K edges (C-row weights now; carried as upper weights next iter)
        float V1  = edgew(b1,k1,WS1), V2  = edgew(b2,k2,WS1), V3  = edgew(b3,k3,WS1), V4 = edgew(b4,k4,WS1);
        float DL1 = edgew(b1,k0,WS2), DL2 = edgew(b2,k1,WS2), DL3 = edgew(b3,k2,WS2),
              DL4 = edgew(b4,k3,WS2), DL5 = edgew(b5,k4,WS2);
        float DR0 = edgew(b0,k1,WS2), DR1 = edgew(b1,k2,WS2), DR2 = edgew(b2,k3,WS2),
              DR3 = edgew(b3,k4,WS2), DR4 = edgew(b4,k5,WS2);

#define PIXEL(am,ac,ap, bm,bc,bp, km,kc,kp, wAL,wAC,wAR, wBL,wBR, wCL,wCV,wCR) { \
        float num = bc; \
        num = fmaf(wAL, am, num); num = fmaf(wAC, ac, num); num = fmaf(wAR, ap, num); \
        num = fmaf(wBL, bm, num); num = fmaf(wBR, bp, num); \
        num = fmaf(wCL, km, num); num = fmaf(wCV, kc, num); num = fmaf(wCR, kp, num); \
        float den = 1.0f + (((wAL + wAC) + (wAR + wBL)) + ((wBR + wCL) + (wCV + wCR))); \
        psum = fmaf(num, __builtin_amdgcn_rcpf(den), psum); }

        PIXEL(a0,a1,a2, b0,b1,b2, k0,k1,k2, pDR0,pV1,pDL2, H0,H1, DL1,V1,DR1)
        PIXEL(a1,a2,a3, b1,b2,b3, k1,k2,k3, pDR1,pV2,pDL3, H1,H2, DL2,V2,DR2)
        PIXEL(a2,a3,a4, b2,b3,b4, k2,k3,k4, pDR2,pV3,pDL4, H2,H3, DL3,V3,DR3)
        PIXEL(a3,a4,a5, b3,b4,b5, k3,k4,k5, pDR3,pV4,pDL5, H3,H4, DL4,V4,DR4)
#undef PIXEL

        // rotate rows (fully unrolled -> pure renaming)
        a0=b0;a1=b1;a2=b2;a3=b3;a4=b4;a5=b5;
        b0=k0;b1=k1;b2=k2;b3=k3;b4=k4;b5=k5;
        k0=p0;k1=p1;k2=p2;k3=p3;k4=p4;k5=p5;
        // carried upper weights = this iter's B-K edges
        pV1=V1;  pV2=V2;  pV3=V3;  pV4=V4;
        pDL2=DL2;pDL3=DL3;pDL4=DL4;pDL5=DL5;
        pDR0=DR0;pDR1=DR1;pDR2=DR2;pDR3=DR3;
        if (r < 6) { LOADROW(r+3, p0,p1,p2,p3,p4,p5) }
    }
#undef LOADROW

    // pool block = 16 cols = 4 lanes (4 cols each); 8 rows accumulated here
    psum += __shfl_xor(psum, 1);
    psum += __shfl_xor(psum, 2);

    // combine the two half-strips: one f32 atomic per pool cell per block.
    // (two commutative adds onto 0 -> bit-deterministic result)
    if ((t & 3) == 0) {
        atomicAdd(&out[(size_t)((b << 6) + pr) * 64 + (t >> 2)], psum * (1.0f / 256.0f));
    }
}

extern "C" void kernel_launch(void* const* d_in, const int* in_sizes, int n_in,
                              void* d_out, int out_size, void* d_ws, size_t ws_size,
                              hipStream_t stream) {
    const float* x = (const float*)d_in[0];
    float* out     = (float*)d_out;
    // zero the accumulation target (graph-capture-safe, stream-ordered)
    hipMemsetAsync(out, 0, (size_t)out_size * sizeof(float), stream);
    // grid: 16 batches * 64 pool rows * 2 half-strips = 2048 blocks of 256 threads
    // = 8 blocks/CU x 4 waves = 32 waves/CU (full residency, single round)
    EdgePreserve_kernel<<<dim3(16 * 64 * 2), dim3(256), 0, stream>>>(x, out);
}

// Round 12
// 28.527 us; speedup vs baseline: 1.2095x; 1.0816x over previous
//
#include <hip/hip_runtime.h>

#define IMG_H 1024
#define IMG_W 1024

#define CC  (-0.1803368801111244f)     // -(1/8)*log2(e)
#define WS1 (-2.8853900817779270e-4f)  // log2(exp(-1/5000))
#define WS2 (-5.7707801635558540e-4f)  // log2(exp(-2/5000))

__device__ __forceinline__ float edgew(float u, float v, float ws) {
    float d = u - v;
    return __builtin_amdgcn_exp2f(fmaf(d * d, CC, ws));
}

// R7 structure; launch_bounds(256,2) unlocks VGPRs (ILP), unroll 4 keeps the
// body I$-resident and matches the 4-buffer ring period (no back-edge movs).
__global__ __launch_bounds__(256, 2) void EdgePreserve_kernel(const float* __restrict__ x,
                                                              float* __restrict__ out) {
    const int t   = threadIdx.x;
    const int bid = blockIdx.x;         // b*64 + pool_row
    const int b   = bid >> 6;
    const int pr  = bid & 63;
    const int r0  = pr << 4;
    const int c0  = t << 2;             // 4 cols per thread; block covers full row

    const float* base = x + (size_t)b * (IMG_H * IMG_W);
    const int cl = (c0 == 0) ? 1 : c0 - 1;                 // reflect left halo col
    const int cr = (c0 + 4 >= IMG_W) ? IMG_W - 2 : c0 + 4; // reflect right halo col

    // 4 row buffers, named scalars: a=r-1, b=r, k=r+1, p=prefetch(r+2..r+3)
    float a0,a1,a2,a3,a4,a5, b0,b1,b2,b3,b4,b5, k0,k1,k2,k3,k4,k5, p0,p1,p2,p3,p4,p5;

#define LOADROW(q, d0,d1,d2,d3,d4,d5) { \
    int _r = r0 + (q); \
    int _rr = (_r < 0) ? -_r : ((_r >= IMG_H) ? (2*IMG_H-2-_r) : _r); \
    const float* _rp = base + _rr * IMG_W; \
    float4 _v = *reinterpret_cast<const float4*>(_rp + c0); \
    d0 = _rp[cl]; d1 = _v.x; d2 = _v.y; d3 = _v.z; d4 = _v.w; d5 = _rp[cr]; }

    LOADROW(-1, a0,a1,a2,a3,a4,a5)
    LOADROW( 0, b0,b1,b2,b3,b4,b5)
    LOADROW( 1, k0,k1,k2,k3,k4,k5)
    LOADROW( 2, p0,p1,p2,p3,p4,p5)

    // carried upper-row edges (between rows r0-1 and r0):
    float pV1 = edgew(a1,b1,WS1), pV2 = edgew(a2,b2,WS1), pV3 = edgew(a3,b3,WS1), pV4 = edgew(a4,b4,WS1);
    float pDL2 = edgew(a2,b1,WS2), pDL3 = edgew(a3,b2,WS2), pDL4 = edgew(a4,b3,WS2), pDL5 = edgew(a5,b4,WS2);
    float pDR0 = edgew(a0,b1,WS2), pDR1 = edgew(a1,b2,WS2), pDR2 = edgew(a2,b3,WS2), pDR3 = edgew(a3,b4,WS2);

    float psum = 0.0f;

    // unroll 4 = ring period: register assignment identical at back-edge.
    #pragma unroll 4
    for (int r = 0; r < 16; ++r) {
        // horizontal edges within row B
        float H0 = edgew(b0,b1,WS1), H1 = edgew(b1,b2,WS1), H2 = edgew(b2,b3,WS1),
              H3 = edgew(b3,b4,WS1), H4 = edgew(b4,b5,WS1);
        // B-K edges (C-row weights now; carried as upper weights next iter)
        float V1  = edgew(b1,k1,WS1), V2  = edgew(b2,k2,WS1), V3  = edgew(b3,k3,WS1), V4 = edgew(b4,k4,WS1);
        float DL1 = edgew(b1,k0,WS2), DL2 = edgew(b2,k1,WS2), DL3 = edgew(b3,k2,WS2),
              DL4 = edgew(b4,k3,WS2), DL5 = edgew(b5,k4,WS2);
        float DR0 = edgew(b0,k1,WS2), DR1 = edgew(b1,k2,WS2), DR2 = edgew(b2,k3,WS2),
              DR3 = edgew(b3,k4,WS2), DR4 = edgew(b4,k5,WS2);

#define PIXEL(am,ac,ap, bm,bc,bp, km,kc,kp, wAL,wAC,wAR, wBL,wBR, wCL,wCV,wCR) { \
        float num = bc; \
        num = fmaf(wAL, am, num); num = fmaf(wAC, ac, num); num = fmaf(wAR, ap, num); \
        num = fmaf(wBL, bm, num); num = fmaf(wBR, bp, num); \
        num = fmaf(wCL, km, num); num = fmaf(wCV, kc, num); num = fmaf(wCR, kp, num); \
        float den = 1.0f + (((wAL + wAC) + (wAR + wBL)) + ((wBR + wCL) + (wCV + wCR))); \
        psum = fmaf(num, __builtin_amdgcn_rcpf(den), psum); }

        PIXEL(a0,a1,a2, b0,b1,b2, k0,k1,k2, pDR0,pV1,pDL2, H0,H1, DL1,V1,DR1)
        PIXEL(a1,a2,a3, b1,b2,b3, k1,k2,k3, pDR1,pV2,pDL3, H1,H2, DL2,V2,DR2)
        PIXEL(a2,a3,a4, b2,b3,b4, k2,k3,k4, pDR2,pV3,pDL4, H2,H3, DL3,V3,DR3)
        PIXEL(a3,a4,a5, b3,b4,b5, k3,k4,k5, pDR3,pV4,pDL5, H3,H4, DL4,V4,DR4)
#undef PIXEL

        // rotate rows (period-4 ring under unroll 4 -> no real movs)
        a0=b0;a1=b1;a2=b2;a3=b3;a4=b4;a5=b5;
        b0=k0;b1=k1;b2=k2;b3=k3;b4=k4;b5=k5;
        k0=p0;k1=p1;k2=p2;k3=p3;k4=p4;k5=p5;
        // carried upper weights = this iter's B-K edges
        pV1=V1;  pV2=V2;  pV3=V3;  pV4=V4;
        pDL2=DL2;pDL3=DL3;pDL4=DL4;pDL5=DL5;
        pDR0=DR0;pDR1=DR1;pDR2=DR2;pDR3=DR3;
        // branchless prefetch: rows r0+17/r0+18 are valid after reflect clamp
        LOADROW(r+3, p0,p1,p2,p3,p4,p5)
    }
#undef LOADROW

    // pool block = 16 cols = 4 lanes (4 cols each); 16 rows accumulated
    psum += __shfl_xor(psum, 1);
    psum += __shfl_xor(psum, 2);

    if ((t & 3) == 0) {
        out[(size_t)bid * 64 + (t >> 2)] = psum * (1.0f / 256.0f);
    }
}

extern "C" void kernel_launch(void* const* d_in, const int* in_sizes, int n_in,
                              void* d_out, int out_size, void* d_ws, size_t ws_size,
                              hipStream_t stream) {
    const float* x = (const float*)d_in[0];
    float* out     = (float*)d_out;
    // grid: 16 batches * 64 pool rows = 1024 blocks of 256 threads (4 cols x 16 rows)
    EdgePreserve_kernel<<<dim3(16 * 64), dim3(256), 0, stream>>>(x, out);
}

// Round 13
// 25.075 us; speedup vs baseline: 1.3760x; 1.1377x over previous
//
#include <hip/hip_runtime.h>

#define IMG_H 1024
#define IMG_W 1024

#define CC  (-0.1803368801111244f)     // -(1/8)*log2(e)
#define WS1 (-2.8853900817779270e-4f)  // log2(exp(-1/5000))
#define WS2 (-5.7707801635558540e-4f)  // log2(exp(-2/5000))

typedef __attribute__((ext_vector_type(2))) float f32x2;

__device__ __forceinline__ float e2(float y) { return __builtin_amdgcn_exp2f(y); }

// packed edge-arg: fma(d*d, CC, ws) over a pixel pair -> v_pk_mul/v_pk_fma
__device__ __forceinline__ f32x2 earg2(f32x2 u, f32x2 v, float ws) {
    f32x2 d = u - v;
    return __builtin_elementwise_fma(d * d, (f32x2)CC, (f32x2)ws);
}
__device__ __forceinline__ float earg1(float u, float v, float ws) {
    float d = u - v;
    return fmaf(d * d, CC, ws);
}

__global__ __launch_bounds__(256) void EdgePreserve_kernel(const float* __restrict__ x,
                                                           float* __restrict__ out) {
    const int t   = threadIdx.x;
    const int bid = blockIdx.x;         // b*64 + pool_row
    const int b   = bid >> 6;
    const int pr  = bid & 63;
    const int r0  = pr << 4;
    const int c0  = t << 2;             // 4 cols per thread

    const float* base = x + (size_t)b * (IMG_H * IMG_W);
    const int cl = (c0 == 0) ? 1 : c0 - 1;
    const int cr = (c0 + 4 >= IMG_W) ? IMG_W - 2 : c0 + 4;

    float a0,a1,a2,a3,a4,a5, b0,b1,b2,b3,b4,b5, k0,k1,k2,k3,k4,k5, p0,p1,p2,p3,p4,p5;

#define LOADROW(q, d0,d1,d2,d3,d4,d5) { \
    int _r = r0 + (q); \
    int _rr = (_r < 0) ? -_r : ((_r >= IMG_H) ? (2*IMG_H-2-_r) : _r); \
    const float* _rp = base + _rr * IMG_W; \
    float4 _v = *reinterpret_cast<const float4*>(_rp + c0); \
    d0 = _rp[cl]; d1 = _v.x; d2 = _v.y; d3 = _v.z; d4 = _v.w; d5 = _rp[cr]; }

    LOADROW(-1, a0,a1,a2,a3,a4,a5)
    LOADROW( 0, b0,b1,b2,b3,b4,b5)
    LOADROW( 1, k0,k1,k2,k3,k4,k5)
    LOADROW( 2, p0,p1,p2,p3,p4,p5)

    // carried weights between row r-1 (a) and r (b):
    // cV12={pV1,pV2} cV34={pV3,pV4} cDR01={pDR0,pDR1} cDR23={pDR2,pDR3}
    // scalars pDL2..pDL5
    f32x2 cV12, cV34, cDR01, cDR23;
    float pDL2, pDL3, pDL4, pDL5;
    {
        f32x2 aV  = earg2((f32x2){a1,a2}, (f32x2){b1,b2}, WS1);
        f32x2 aVb = earg2((f32x2){a3,a4}, (f32x2){b3,b4}, WS1);
        f32x2 aR  = earg2((f32x2){a0,a1}, (f32x2){b1,b2}, WS2);
        f32x2 aRb = earg2((f32x2){a2,a3}, (f32x2){b3,b4}, WS2);
        f32x2 aL  = earg2((f32x2){a2,a3}, (f32x2){b1,b2}, WS2);
        f32x2 aLb = earg2((f32x2){a4,a5}, (f32x2){b3,b4}, WS2);
        cV12  = (f32x2){e2(aV.x),  e2(aV.y)};
        cV34  = (f32x2){e2(aVb.x), e2(aVb.y)};
        cDR01 = (f32x2){e2(aR.x),  e2(aR.y)};
        cDR23 = (f32x2){e2(aRb.x), e2(aRb.y)};
        pDL2 = e2(aL.x);  pDL3 = e2(aL.y);
        pDL4 = e2(aLb.x); pDL5 = e2(aLb.y);
    }

    f32x2 psum = (f32x2){0.0f, 0.0f};

    #pragma unroll
    for (int r = 0; r < 16; ++r) {
        // pair views of the rows (cross pairs left to regalloc)
        f32x2 a01={a0,a1}, a12={a1,a2}, a23={a2,a3}, a34={a3,a4}, a45={a4,a5};
        f32x2 b01={b0,b1}, b12={b1,b2}, b23={b2,b3}, b34={b3,b4}, b45={b4,b5};
        f32x2 k01={k0,k1}, k12={k1,k2}, k23={k2,k3}, k34={k3,k4}, k45={k4,k5};

        // packed edge args (8 pk chains + 3 scalar)
        f32x2 aH01 = earg2(b01, b12, WS1);   // H0,H1
        f32x2 aH23 = earg2(b23, b34, WS1);   // H2,H3
        float aH4  = earg1(b4, b5, WS1);     // H4
        f32x2 aV12 = earg2(b12, k12, WS1);   // V1,V2
        f32x2 aV34 = earg2(b34, k34, WS1);   // V3,V4
        f32x2 aDL12 = earg2(b12, k01, WS2);  // DL1,DL2
        f32x2 aDL34 = earg2(b34, k23, WS2);  // DL3,DL4
        float aDL5  = earg1(b5, k4, WS2);    // DL5
        f32x2 aDR01 = earg2(b01, k12, WS2);  // DR0,DR1
        f32x2 aDR23 = earg2(b23, k34, WS2);  // DR2,DR3
        float aDR4  = earg1(b4, k5, WS2);    // DR4

        // scalar transcendentals (19)
        float H0 = e2(aH01.x), H1 = e2(aH01.y), H2 = e2(aH23.x), H3 = e2(aH23.y), H4 = e2(aH4);
        float V1 = e2(aV12.x), V2 = e2(aV12.y), V3 = e2(aV34.x), V4 = e2(aV34.y);
        float DL1 = e2(aDL12.x), DL2 = e2(aDL12.y), DL3 = e2(aDL34.x), DL4 = e2(aDL34.y), DL5 = e2(aDL5);
        float DR0 = e2(aDR01.x), DR1 = e2(aDR01.y), DR2 = e2(aDR23.x), DR3 = e2(aDR23.y), DR4 = e2(aDR4);

        f32x2 H01={H0,H1}, H12={H1,H2}, H23={H2,H3}, H34={H3,H4};
        f32x2 V12={V1,V2}, V34={V3,V4};
        f32x2 DL12={DL1,DL2}, DL34={DL3,DL4};
        f32x2 DR01={DR0,DR1}, DR23={DR2,DR3};

#define PIXPAIR(ctr, nAL,nAC,nAR, nBL,nBR, nKL,nKC,nKR, wAL,wAC,wAR, wBL,wBR, wKL,wKC,wKR) { \
        f32x2 num = ctr; \
        num = __builtin_elementwise_fma(wAL, nAL, num); \
        num = __builtin_elementwise_fma(wAC, nAC, num); \
        num = __builtin_elementwise_fma(wAR, nAR, num); \
        num = __builtin_elementwise_fma(wBL, nBL, num); \
        num = __builtin_elementwise_fma(wBR, nBR, num); \
        num = __builtin_elementwise_fma(wKL, nKL, num); \
        num = __builtin_elementwise_fma(wKC, nKC, num); \
        num = __builtin_elementwise_fma(wKR, nKR, num); \
        f32x2 den = ((wAL + wAC) + (wAR + wBL)) + ((wBR + wKL) + (wKC + wKR)); \
        den = den + (f32x2)1.0f; \
        f32x2 rc = (f32x2){__builtin_amdgcn_rcpf(den.x), __builtin_amdgcn_rcpf(den.y)}; \
        psum = __builtin_elementwise_fma(num, rc, psum); }

        // pixels (p0,p1): centers {b1,b2}
        PIXPAIR(b12, a01,a12,a23, b01,b23, k01,k12,k23,
                cDR01, cV12, ((f32x2){pDL2,pDL3}), H01, H12, DL12, V12, ((f32x2){DR1,DR2}))
        // pixels (p2,p3): centers {b3,b4}
        PIXPAIR(b34, a23,a34,a45, b23,b45, k23,k34,k45,
                cDR23, cV34, ((f32x2){pDL4,pDL5}), H23, H34, DL34, V34, ((f32x2){DR3,DR4}))
#undef PIXPAIR

        // rotate rows (full unroll -> renaming)
        a0=b0;a1=b1;a2=b2;a3=b3;a4=b4;a5=b5;
        b0=k0;b1=k1;b2=k2;b3=k3;b4=k4;b5=k5;
        k0=p0;k1=p1;k2=p2;k3=p3;k4=p4;k5=p5;
        // carried weights = this row's B-K edges
        cV12 = V12; cV34 = V34; cDR01 = DR01; cDR23 = DR23;
        pDL2 = DL2; pDL3 = DL3; pDL4 = DL4; pDL5 = DL5;
        if (r < 14) { LOADROW(r+3, p0,p1,p2,p3,p4,p5) }
    }
#undef LOADROW

    float ps = psum.x + psum.y;
    ps += __shfl_xor(ps, 1);
    ps += __shfl_xor(ps, 2);

    if ((t & 3) == 0) {
        out[(size_t)bid * 64 + (t >> 2)] = ps * (1.0f / 256.0f);
    }
}

extern "C" void kernel_launch(void* const* d_in, const int* in_sizes, int n_in,
                              void* d_out, int out_size, void* d_ws, size_t ws_size,
                              hipStream_t stream) {
    const float* x = (const float*)d_in[0];
    float* out     = (float*)d_out;
    EdgePreserve_kernel<<<dim3(16 * 64), dim3(256), 0, stream>>>(x, out);
}

// Round 14
// 24.730 us; speedup vs baseline: 1.3952x; 1.0139x over previous
//
#include <hip/hip_runtime.h>

#define IMG_H 1024
#define IMG_W 1024

#define CC  (-0.1803368801111244f)     // -(1/8)*log2(e)
#define WS1 (-2.8853900817779270e-4f)  // log2(exp(-1/5000))
#define WS2 (-5.7707801635558540e-4f)  // log2(exp(-2/5000))

typedef __attribute__((ext_vector_type(2))) float f32x2;

__device__ __forceinline__ float e2(float y) { return __builtin_amdgcn_exp2f(y); }

__device__ __forceinline__ f32x2 earg2(f32x2 u, f32x2 v, float ws) {
    f32x2 d = u - v;
    return __builtin_elementwise_fma(d * d, (f32x2)CC, (f32x2)ws);
}
__device__ __forceinline__ float earg1(float u, float v, float ws) {
    float d = u - v;
    return fmaf(d * d, CC, ws);
}

// 14 edges between rows X (upper) and Y (lower):
// V_c=w(X_c,Y_c), DL_c=w(X_c,Y_{c-1}), DR_c=w(X_c,Y_{c+1})
#define ROWPAIR_EDGES(X0,X1,X2,X3,X4,X5, Y0,Y1,Y2,Y3,Y4,Y5, \
                      V1,V2,V3,V4, DL1,DL2,DL3,DL4,DL5, DR0,DR1,DR2,DR3,DR4) { \
    f32x2 aV12  = earg2((f32x2){X1,X2}, (f32x2){Y1,Y2}, WS1); \
    f32x2 aV34  = earg2((f32x2){X3,X4}, (f32x2){Y3,Y4}, WS1); \
    f32x2 aDL12 = earg2((f32x2){X1,X2}, (f32x2){Y0,Y1}, WS2); \
    f32x2 aDL34 = earg2((f32x2){X3,X4}, (f32x2){Y2,Y3}, WS2); \
    float aDL5  = earg1(X5, Y4, WS2); \
    f32x2 aDR01 = earg2((f32x2){X0,X1}, (f32x2){Y1,Y2}, WS2); \
    f32x2 aDR23 = earg2((f32x2){X2,X3}, (f32x2){Y3,Y4}, WS2); \
    float aDR4  = earg1(X4, Y5, WS2); \
    V1 = e2(aV12.x);  V2 = e2(aV12.y);  V3 = e2(aV34.x);  V4 = e2(aV34.y); \
    DL1 = e2(aDL12.x); DL2 = e2(aDL12.y); DL3 = e2(aDL34.x); DL4 = e2(aDL34.y); DL5 = e2(aDL5); \
    DR0 = e2(aDR01.x); DR1 = e2(aDR01.y); DR2 = e2(aDR23.x); DR3 = e2(aDR23.y); DR4 = e2(aDR4); }

// 5 horizontal edges within row X: H_c = w(X_c, X_{c+1})
#define ROW_H(X0,X1,X2,X3,X4,X5, H0,H1,H2,H3,H4) { \
    f32x2 aH01 = earg2((f32x2){X0,X1}, (f32x2){X1,X2}, WS1); \
    f32x2 aH23 = earg2((f32x2){X2,X3}, (f32x2){X3,X4}, WS1); \
    float aH4  = earg1(X4, X5, WS1); \
    H0 = e2(aH01.x); H1 = e2(aH01.y); H2 = e2(aH23.x); H3 = e2(aH23.y); H4 = e2(aH4); }

__global__ __launch_bounds__(256, 4) void EdgePreserve_kernel(const float* __restrict__ x,
                                                              float* __restrict__ out) {
    const int t   = threadIdx.x;
    const int bid = blockIdx.x;         // b*64 + pool_row
    const int b   = bid >> 6;
    const int pr  = bid & 63;
    const int r0  = pr << 4;
    const int c0  = t << 2;             // 4 cols per thread

    const float* base = x + (size_t)b * (IMG_H * IMG_W);
    const int cl = (c0 == 0) ? 1 : c0 - 1;
    const int cr = (c0 + 4 >= IMG_W) ? IMG_W - 2 : c0 + 4;

    // 6 row buffers: A=r-1, B=r, C=r+1, D=r+2; E,F = prefetch r+3, r+4
    float a0,a1,a2,a3,a4,a5, b0,b1,b2,b3,b4,b5, c1_0,c1_1,c1_2,c1_3,c1_4,c1_5,
          d0,d1,d2,d3,d4,d5, e0,e1,e2_,e3,e4,e5, f0,f1,f2,f3,f4,f5;

#define LOADROW(q, w0,w1,w2,w3,w4,w5) { \
    int _r = r0 + (q); \
    int _rr = (_r < 0) ? -_r : ((_r >= IMG_H) ? (2*IMG_H-2-_r) : _r); \
    const float* _rp = base + _rr * IMG_W; \
    float4 _v = *reinterpret_cast<const float4*>(_rp + c0); \
    w0 = _rp[cl]; w1 = _v.x; w2 = _v.y; w3 = _v.z; w4 = _v.w; w5 = _rp[cr]; }

    LOADROW(-1, a0,a1,a2,a3,a4,a5)
    LOADROW( 0, b0,b1,b2,b3,b4,b5)
    LOADROW( 1, c1_0,c1_1,c1_2,c1_3,c1_4,c1_5)
    LOADROW( 2, d0,d1,d2,d3,d4,d5)

    // carried A-B edges (rows r0-1, r0): 12 values
    f32x2 cV12, cV34, cDR01, cDR23;
    float pDL2, pDL3, pDL4, pDL5;
    {
        f32x2 aV  = earg2((f32x2){a1,a2}, (f32x2){b1,b2}, WS1);
        f32x2 aVb = earg2((f32x2){a3,a4}, (f32x2){b3,b4}, WS1);
        f32x2 aR  = earg2((f32x2){a0,a1}, (f32x2){b1,b2}, WS2);
        f32x2 aRb = earg2((f32x2){a2,a3}, (f32x2){b3,b4}, WS2);
        f32x2 aL  = earg2((f32x2){a2,a3}, (f32x2){b1,b2}, WS2);
        f32x2 aLb = earg2((f32x2){a4,a5}, (f32x2){b3,b4}, WS2);
        cV12  = (f32x2){e2(aV.x),  e2(aV.y)};
        cV34  = (f32x2){e2(aVb.x), e2(aVb.y)};
        cDR01 = (f32x2){e2(aR.x),  e2(aR.y)};
        cDR23 = (f32x2){e2(aRb.x), e2(aRb.y)};
        pDL2 = e2(aL.x);  pDL3 = e2(aL.y);
        pDL4 = e2(aLb.x); pDL5 = e2(aLb.y);
    }

    f32x2 psum = (f32x2){0.0f, 0.0f};

#define PIXPAIR(ctr, nAL,nAC,nAR, nBL,nBR, nKL,nKC,nKR, wAL,wAC,wAR, wBL,wBR, wKL,wKC,wKR) { \
        f32x2 num = ctr; \
        num = __builtin_elementwise_fma(wAL, nAL, num); \
        num = __builtin_elementwise_fma(wAC, nAC, num); \
        num = __builtin_elementwise_fma(wAR, nAR, num); \
        num = __builtin_elementwise_fma(wBL, nBL, num); \
        num = __builtin_elementwise_fma(wBR, nBR, num); \
        num = __builtin_elementwise_fma(wKL, nKL, num); \
        num = __builtin_elementwise_fma(wKC, nKC, num); \
        num = __builtin_elementwise_fma(wKR, nKR, num); \
        f32x2 den = ((wAL + wAC) + (wAR + wBL)) + ((wBR + wKL) + (wKC + wKR)); \
        den = den + (f32x2)1.0f; \
        f32x2 rc = (f32x2){__builtin_amdgcn_rcpf(den.x), __builtin_amdgcn_rcpf(den.y)}; \
        psum = __builtin_elementwise_fma(num, rc, psum); }

    // 8 fused iterations, 2 image rows each; fully unrolled
    #pragma unroll
    for (int i = 0; i < 8; ++i) {
        // prefetch rows 2i+3, 2i+4 (consumed next iteration as C,D)
        LOADROW(2*i + 3, e0,e1,e2_,e3,e4,e5)
        LOADROW(2*i + 4, f0,f1,f2,f3,f4,f5)

        // horizontal edges of B and C
        float HB0,HB1,HB2,HB3,HB4, HC0,HC1,HC2,HC3,HC4;
        ROW_H(b0,b1,b2,b3,b4,b5, HB0,HB1,HB2,HB3,HB4)
        ROW_H(c1_0,c1_1,c1_2,c1_3,c1_4,c1_5, HC0,HC1,HC2,HC3,HC4)

        // B-C and C-D edge sets (14 each)
        float BV1,BV2,BV3,BV4, BDL1,BDL2,BDL3,BDL4,BDL5, BDR0,BDR1,BDR2,BDR3,BDR4;
        float CV1,CV2,CV3,CV4, CDL1,CDL2,CDL3,CDL4,CDL5, CDR0,CDR1,CDR2,CDR3,CDR4;
        ROWPAIR_EDGES(b0,b1,b2,b3,b4,b5, c1_0,c1_1,c1_2,c1_3,c1_4,c1_5,
                      BV1,BV2,BV3,BV4, BDL1,BDL2,BDL3,BDL4,BDL5, BDR0,BDR1,BDR2,BDR3,BDR4)
        ROWPAIR_EDGES(c1_0,c1_1,c1_2,c1_3,c1_4,c1_5, d0,d1,d2,d3,d4,d5,
                      CV1,CV2,CV3,CV4, CDL1,CDL2,CDL3,CDL4,CDL5, CDR0,CDR1,CDR2,CDR3,CDR4)

        // pair views
        f32x2 a01={a0,a1}, a12={a1,a2}, a23={a2,a3}, a34={a3,a4}, a45={a4,a5};
        f32x2 b01={b0,b1}, b12={b1,b2}, b23={b2,b3}, b34={b3,b4}, b45={b4,b5};
        f32x2 c01={c1_0,c1_1}, c12={c1_1,c1_2}, c23={c1_2,c1_3}, c34={c1_3,c1_4}, c45={c1_4,c1_5};
        f32x2 d01={d0,d1}, d12={d1,d2}, d23={d2,d3}, d34={d3,d4}, d45={d4,d5};

        // ---- image row 2i (center B): up = carried A-B, down = B-C ----
        PIXPAIR(b12, a01,a12,a23, b01,b23, c01,c12,c23,
                cDR01, cV12, ((f32x2){pDL2,pDL3}),
                ((f32x2){HB0,HB1}), ((f32x2){HB1,HB2}),
                ((f32x2){BDL1,BDL2}), ((f32x2){BV1,BV2}), ((f32x2){BDR1,BDR2}))
        PIXPAIR(b34, a23,a34,a45, b23,b45, c23,c34,c45,
                cDR23, cV34, ((f32x2){pDL4,pDL5}),
                ((f32x2){HB2,HB3}), ((f32x2){HB3,HB4}),
                ((f32x2){BDL3,BDL4}), ((f32x2){BV3,BV4}), ((f32x2){BDR3,BDR4}))

        // ---- image row 2i+1 (center C): up = B-C, down = C-D ----
        PIXPAIR(c12, b01,b12,b23, c01,c23, d01,d12,d23,
                ((f32x2){BDR0,BDR1}), ((f32x2){BV1,BV2}), ((f32x2){BDL2,BDL3}),
                ((f32x2){HC0,HC1}), ((f32x2){HC1,HC2}),
                ((f32x2){CDL1,CDL2}), ((f32x2){CV1,CV2}), ((f32x2){CDR1,CDR2}))
        PIXPAIR(c34, b23,b34,b45, c23,c45, d23,d34,d45,
                ((f32x2){BDR2,BDR3}), ((f32x2){BV3,BV4}), ((f32x2){BDL4,BDL5}),
                ((f32x2){HC2,HC3}), ((f32x2){HC3,HC4}),
                ((f32x2){CDL3,CDL4}), ((f32x2){CV3,CV4}), ((f32x2){CDR3,CDR4}))

        // rotate rows by 2 (full unroll -> renaming)
        a0=c1_0;a1=c1_1;a2=c1_2;a3=c1_3;a4=c1_4;a5=c1_5;
        b0=d0;b1=d1;b2=d2;b3=d3;b4=d4;b5=d5;
        c1_0=e0;c1_1=e1;c1_2=e2_;c1_3=e3;c1_4=e4;c1_5=e5;
        d0=f0;d1=f1;d2=f2;d3=f3;d4=f4;d5=f5;
        // carried = this iter's C-D edges
        cV12 = (f32x2){CV1,CV2}; cV34 = (f32x2){CV3,CV4};
        cDR01 = (f32x2){CDR0,CDR1}; cDR23 = (f32x2){CDR2,CDR3};
        pDL2 = CDL2; pDL3 = CDL3; pDL4 = CDL4; pDL5 = CDL5;
    }
#undef PIXPAIR
#undef LOADROW

    float ps = psum.x + psum.y;
    ps += __shfl_xor(ps, 1);
    ps += __shfl_xor(ps, 2);

    if ((t & 3) == 0) {
        out[(size_t)bid * 64 + (t >> 2)] = ps * (1.0f / 256.0f);
    }
}

extern "C" void kernel_launch(void* const* d_in, const int* in_sizes, int n_in,
                              void* d_out, int out_size, void* d_ws, size_t ws_size,
                              hipStream_t stream) {
    const float* x = (const float*)d_in[0];
    float* out     = (float*)d_out;
    // 1024 blocks x 256 threads (4 cols x 16 rows each), 4 blocks/CU resident
    EdgePreserve_kernel<<<dim3(16 * 64), dim3(256), 0, stream>>>(x, out);
}